// Round 14
// baseline (398.143 us; speedup 1.0000x reference)
//
#include <hip/hip_runtime.h>
#include <hip/hip_bf16.h>

typedef unsigned short u16;
typedef unsigned int u32;
typedef __attribute__((ext_vector_type(8))) short bf16x8;   // 8 bf16 = 4 VGPRs
typedef __attribute__((ext_vector_type(4))) short bf16x4;
typedef __attribute__((ext_vector_type(4))) float f32x4;

#define NBG   5000
#define NPID  5532
#define NTOT  15532      // 5000 + 5532 + 5000
#define FEAT  256
#define BATCH 4096
#define SCALE_LOG2E 43.280851226668994f   // 30 * log2(e)
#define LPITCH 264       // f32-fallback LDS pitch (shorts)

#define NTILE_B  976             // 61 chunks x 16 tiles; 971 real, 5 zero-pad
#define TILE_SH  4096            // shorts per 16-col tile (16*256)
#define NTILE_A  256             // 4096 rows / 16

// ---- workspace layout (bytes) ----
#define TABT_BYTES ((size_t)NTILE_B * TILE_SH * 2)   // 7,995,392
#define AT_BYTES   ((size_t)NTILE_A * TILE_SH * 2)   // 2,097,152
#define SUMS_OFF   (TABT_BYTES + AT_BYTES)
// S floats: [0,4096) bg | [4096,8192) nb | 8192 det | 8193 oim | 8194 nv
//           | 8195 ticket(u32)
#define SUMS_FLOATS 8196
#define WS_NEED    (SUMS_OFF + SUMS_FLOATS * 4)

__device__ __forceinline__ void atomic_add_f(float* p, float v) {
    __hip_atomic_fetch_add(p, v, __ATOMIC_RELAXED, __HIP_MEMORY_SCOPE_AGENT);
}
__device__ __forceinline__ float atomic_ld_f(const float* p) {
    return __hip_atomic_load(p, __ATOMIC_RELAXED, __HIP_MEMORY_SCOPE_AGENT);
}
__device__ __forceinline__ short f2bf(float f) {
    return (short)__bfloat16_as_ushort(__float2bfloat16(f));
}
__device__ __forceinline__ float bf2f(u16 u) {
    union { u32 i; float f; } v; v.i = ((u32)u) << 16; return v.f;
}

__device__ __forceinline__ const float* table_row(
    int n, const float* __restrict__ lut, const float* __restrict__ cq,
    const float* __restrict__ cqb)
{
    const int nc = n < NTOT ? n : NTOT - 1;
    if (nc < NBG)        return cqb + (size_t)nc * FEAT;
    if (nc < NBG + NPID) return lut + (size_t)(nc - NBG) * FEAT;
    return cq + (size_t)(nc - NBG - NPID) * FEAT;
}

// -------- Stage 0: f32 -> bf16 tiled prepass via LDS transpose -------------
// Tile layout (8192 B): short off = kk*512 + q*128 + col*8 (+sub), holding
// src[col][kk*32 + q*8 .. +8].  Both global directions coalesced.
#define PRE_BLOCKS (NTILE_B + NTILE_A)   // 1232

__global__ __launch_bounds__(256) void prepass_kernel(
    const float* __restrict__ inputs, const float* __restrict__ lut,
    const float* __restrict__ cq, const float* __restrict__ cqb,
    u16* __restrict__ tabt, u16* __restrict__ at, float* __restrict__ S)
{
    __shared__ __align__(16) short tl[TILE_SH];
    const int b = blockIdx.x, tid = threadIdx.x;
    const int fid = b * 256 + tid;
    if (fid < SUMS_FLOATS) S[fid] = 0.f;

    const bool isA = (b >= NTILE_B);
    const int tile = isA ? (b - NTILE_B) : b;
    u16* dst = (isA ? at : tabt) + (size_t)tile * TILE_SH;

    const int row = tid >> 4;          // 0..15 (source row within tile)
    const int c16 = tid & 15;          // 16-float chunk within the row
    bool ok = true;
    const float* src;
    if (isA) {
        src = inputs + (size_t)(tile * 16 + row) * FEAT + c16 * 16;
    } else {
        const int cg = tile * 16 + row;
        ok = cg < NTOT;
        src = table_row(cg, lut, cq, cqb) + c16 * 16;
    }
    #pragma unroll
    for (int i = 0; i < 4; ++i) {
        const f32x4 v = *(const f32x4*)(src + i * 4);
        const int P = c16 * 16 + i * 4;                   // float pos in row
        const int kk = P >> 5, q = (P >> 3) & 3, sub = P & 7;   // sub in {0,4}
        const bf16x4 h = ok ? bf16x4{ f2bf(v[0]), f2bf(v[1]), f2bf(v[2]), f2bf(v[3]) }
                            : bf16x4{ 0, 0, 0, 0 };
        *(bf16x4*)(tl + kk * 512 + q * 128 + row * 8 + sub) = h;
    }
    __syncthreads();
    *(bf16x8*)(dst + tid * 8)        = *(const bf16x8*)(tl + tid * 8);
    *(bf16x8*)(dst + 2048 + tid * 8) = *(const bf16x8*)(tl + 2048 + tid * 8);
}

// -------- Stage 1: fused GEMM + exp-sum.  NO fences, NO tickets. -----------
// 976 blocks (16 rowchunks x 61 colchunks), XCD-swizzled.
// 2-tile barrier PHASES with 4 LDS buffers (32 KB): write 2 tiles ->
// ONE barrier -> prefetch next 2 tiles -> consume 2 tiles.  Halves the
// barrier count (r13: 16 barriers, MfmaUtil 17%, dur = MFMA-work/Util ->
// stall-bound) and doubles the load-latency cover window.  Hazard: pair-A
// rewrite at phase p+2 is after barrier(p+1), which each wave reaches only
// after its pair-A consume (program order).  Staging regs stay NAMED
// (register-array indexing spills to scratch -- r10).  launch_bounds(256,4)
// so ~4 blocks/CU are co-resident (VGPR 128 fits).
__global__ __launch_bounds__(256, 4) void score_bf16_kernel(
    const u16* __restrict__ tabt, const u16* __restrict__ at,
    float* __restrict__ sum_bg, float* __restrict__ sum_nb)
{
    __shared__ __align__(16) short lbA0[TILE_SH];
    __shared__ __align__(16) short lbA1[TILE_SH];
    __shared__ __align__(16) short lbB0[TILE_SH];
    __shared__ __align__(16) short lbB1[TILE_SH];

    const int lid = blockIdx.x;
    const int x8  = lid & 7;
    const int j   = lid >> 3;                 // [0, 122)
    const int rowchunk = x8 * 2 + (j & 1);    // [0, 16)
    const int colchunk = j >> 1;              // [0, 61)

    const int tid  = threadIdx.x;
    const int wave = tid >> 6;
    const int lane = tid & 63;
    const int l15  = lane & 15;
    const int quad = lane >> 4;

    // A fragments: 4 row-tiles, coalesced 1 KB/wave reads.
    bf16x8 af[4][8];
    {
        const u16* ab = at + (size_t)(rowchunk * 16 + wave * 4) * TILE_SH
                           + quad * 128 + l15 * 8;
        #pragma unroll
        for (int s = 0; s < 4; ++s)
            #pragma unroll
            for (int kk = 0; kk < 8; ++kk)
                af[s][kk] = *(const bf16x8*)(ab + (size_t)s * TILE_SH + kk * 512);
    }

    float pbg[16], pnb[16];
    #pragma unroll
    for (int i = 0; i < 16; ++i) { pbg[i] = 0.f; pnb[i] = 0.f; }

    const int bt0 = colchunk * 16;
    // colchunk 60: tiles 971..975 are zero-pad; run 971 (zeros, okc-masked)
    // so the tile count stays even; 972+ skipped.
    const int nph = (colchunk == 60) ? 6 : 8;      // phases of 2 tiles

    auto loadg = [&](int bt, bf16x8& a, bf16x8& b) {
        const u16* g = tabt + (size_t)bt * TILE_SH;
        a = *(const bf16x8*)(g + tid * 8);
        b = *(const bf16x8*)(g + 2048 + tid * 8);
    };
    auto consume = [&](const short* lb, int bt) {
        f32x4 cc[4];
        #pragma unroll
        for (int s = 0; s < 4; ++s) cc[s] = f32x4{0.f, 0.f, 0.f, 0.f};
        #pragma unroll
        for (int kk = 0; kk < 8; ++kk) {
            const bf16x8 b = *(const bf16x8*)(lb + kk * 512 + quad * 128 + l15 * 8);
            cc[0] = __builtin_amdgcn_mfma_f32_16x16x32_bf16(af[0][kk], b, cc[0], 0, 0, 0);
            cc[1] = __builtin_amdgcn_mfma_f32_16x16x32_bf16(af[1][kk], b, cc[1], 0, 0, 0);
            cc[2] = __builtin_amdgcn_mfma_f32_16x16x32_bf16(af[2][kk], b, cc[2], 0, 0, 0);
            cc[3] = __builtin_amdgcn_mfma_f32_16x16x32_bf16(af[3][kk], b, cc[3], 0, 0, 0);
        }
        if (colchunk != 60) {
            if (bt < 312) {                    // all background
                #pragma unroll
                for (int s = 0; s < 4; ++s)
                    #pragma unroll
                    for (int r = 0; r < 4; ++r)
                        pbg[s * 4 + r] += exp2f(cc[s][r] * SCALE_LOG2E);
            } else if (bt > 312) {             // all non-bg
                #pragma unroll
                for (int s = 0; s < 4; ++s)
                    #pragma unroll
                    for (int r = 0; r < 4; ++r)
                        pnb[s * 4 + r] += exp2f(cc[s][r] * SCALE_LOG2E);
            } else {                           // tile 312: cols 4992..5007
                const bool isbg = l15 < 8;
                #pragma unroll
                for (int s = 0; s < 4; ++s)
                    #pragma unroll
                    for (int r = 0; r < 4; ++r) {
                        const float e = exp2f(cc[s][r] * SCALE_LOG2E);
                        pbg[s * 4 + r] += isbg ? e : 0.f;
                        pnb[s * 4 + r] += isbg ? 0.f : e;
                    }
            }
        } else {                               // last chunk: mask pad cols
            const bool okc = (bt * 16 + l15) < NTOT;
            #pragma unroll
            for (int s = 0; s < 4; ++s)
                #pragma unroll
                for (int r = 0; r < 4; ++r) {
                    const float e = exp2f(cc[s][r] * SCALE_LOG2E);
                    pnb[s * 4 + r] += okc ? e : 0.f;
                }
        }
    };

    // NAMED staging registers for the 2-tile phase (no register arrays).
    bf16x8 ra0, ra1, rb0, rb1;
    loadg(bt0, ra0, ra1);
    loadg(bt0 + 1, rb0, rb1);

    #pragma unroll 1
    for (int ph = 0; ph < nph; ++ph) {
        short* w0 = (ph & 1) ? lbB0 : lbA0;    // LDS address select: no spill
        short* w1 = (ph & 1) ? lbB1 : lbA1;
        *(bf16x8*)(w0 + tid * 8) = ra0;
        *(bf16x8*)(w0 + 2048 + tid * 8) = ra1;
        *(bf16x8*)(w1 + tid * 8) = rb0;
        *(bf16x8*)(w1 + 2048 + tid * 8) = rb1;
        __syncthreads();
        if (ph + 1 < nph) {                    // prefetch next phase's 2 tiles
            loadg(bt0 + 2 * ph + 2, ra0, ra1);
            loadg(bt0 + 2 * ph + 3, rb0, rb1);
        }
        consume(w0, bt0 + 2 * ph);
        consume(w1, bt0 + 2 * ph + 1);
    }

    #pragma unroll
    for (int off = 1; off < 16; off <<= 1) {
        #pragma unroll
        for (int i = 0; i < 16; ++i) {
            pbg[i] += __shfl_xor(pbg[i], off);
            pnb[i] += __shfl_xor(pnb[i], off);
        }
    }
    if (l15 == 0) {
        #pragma unroll
        for (int s = 0; s < 4; ++s) {
            #pragma unroll
            for (int r = 0; r < 4; ++r) {
                const int row = (rowchunk * 16 + wave * 4 + s) * 16 + quad * 4 + r;
                atomic_add_f(&sum_bg[row], pbg[s * 4 + r]);
                atomic_add_f(&sum_nb[row], pnb[s * 4 + r]);
            }
        }
    }
}

// -------- Stage 1 (f32 fallback, round-4 structure, proven) ----------------
__global__ __launch_bounds__(256, 2) void score_f32_kernel(
    const float* __restrict__ inputs, const float* __restrict__ lut,
    const float* __restrict__ cq, const float* __restrict__ cqb,
    float* __restrict__ sum_bg, float* __restrict__ sum_nb)
{
    __shared__ __align__(16) short lds[32 * LPITCH];
    const int wave = threadIdx.x >> 6;
    const int lane = threadIdx.x & 63;
    const int l15  = lane & 15;
    const int quad = lane >> 4;
    const int rowbase = blockIdx.y * 256;
    const int colbase = blockIdx.x * 256;

    bf16x8 afrag[4][8];
    #pragma unroll 1
    for (int c = 0; c < 8; ++c) {
        __syncthreads();
        #pragma unroll
        for (int i = 0; i < 8; ++i) {
            const int lr = i * 4 + wave;
            const f32x4 v = *(const f32x4*)(inputs + (size_t)(rowbase + c * 32 + lr) * FEAT + lane * 4);
            bf16x4 h = { f2bf(v[0]), f2bf(v[1]), f2bf(v[2]), f2bf(v[3]) };
            *(bf16x4*)(&lds[lr * LPITCH + lane * 4]) = h;
        }
        __syncthreads();
        if ((c >> 1) == wave) {
            const int half = c & 1;
            #pragma unroll
            for (int j2 = 0; j2 < 2; ++j2) {
                const int lr = j2 * 16 + l15;
                #pragma unroll
                for (int kk = 0; kk < 8; ++kk)
                    afrag[half * 2 + j2][kk] =
                        *(const bf16x8*)(&lds[lr * LPITCH + kk * 32 + quad * 8]);
            }
        }
    }

    float pbg[16], pnb[16];
    #pragma unroll
    for (int i = 0; i < 16; ++i) { pbg[i] = 0.f; pnb[i] = 0.f; }

    #pragma unroll 1
    for (int s = 0; s < 8; ++s) {
        __syncthreads();
        #pragma unroll
        for (int i = 0; i < 8; ++i) {
            const int lc = i * 4 + wave;
            const f32x4 v = *(const f32x4*)(table_row(colbase + s * 32 + lc, lut, cq, cqb) + lane * 4);
            bf16x4 h = { f2bf(v[0]), f2bf(v[1]), f2bf(v[2]), f2bf(v[3]) };
            *(bf16x4*)(&lds[lc * LPITCH + lane * 4]) = h;
        }
        __syncthreads();

        #pragma unroll
        for (int st = 0; st < 2; ++st) {
            const int lc = st * 16 + l15;
            f32x4 cc[4];
            #pragma unroll
            for (int q = 0; q < 4; ++q) cc[q] = f32x4{0.f, 0.f, 0.f, 0.f};
            #pragma unroll
            for (int kk = 0; kk < 8; ++kk) {
                const bf16x8 b = *(const bf16x8*)(&lds[lc * LPITCH + kk * 32 + quad * 8]);
                cc[0] = __builtin_amdgcn_mfma_f32_16x16x32_bf16(afrag[0][kk], b, cc[0], 0, 0, 0);
                cc[1] = __builtin_amdgcn_mfma_f32_16x16x32_bf16(afrag[1][kk], b, cc[1], 0, 0, 0);
                cc[2] = __builtin_amdgcn_mfma_f32_16x16x32_bf16(afrag[2][kk], b, cc[2], 0, 0, 0);
                cc[3] = __builtin_amdgcn_mfma_f32_16x16x32_bf16(afrag[3][kk], b, cc[3], 0, 0, 0);
            }
            const int n = colbase + s * 32 + st * 16 + l15;
            const bool okc  = n < NTOT;
            const bool isbg = n < NBG;
            #pragma unroll
            for (int q = 0; q < 4; ++q) {
                #pragma unroll
                for (int r = 0; r < 4; ++r) {
                    float e = exp2f(cc[q][r] * SCALE_LOG2E);
                    e = okc ? e : 0.f;
                    pbg[q * 4 + r] += isbg ? e : 0.f;
                    pnb[q * 4 + r] += isbg ? 0.f : e;
                }
            }
        }
    }

    #pragma unroll
    for (int off = 1; off < 16; off <<= 1) {
        #pragma unroll
        for (int i = 0; i < 16; ++i) {
            pbg[i] += __shfl_xor(pbg[i], off);
            pnb[i] += __shfl_xor(pnb[i], off);
        }
    }
    if (l15 == 0) {
        #pragma unroll
        for (int q = 0; q < 4; ++q) {
            #pragma unroll
            for (int r = 0; r < 4; ++r) {
                const int row = rowbase + wave * 64 + q * 16 + quad * 4 + r;
                atomic_add_f(&sum_bg[row], pbg[q * 4 + r]);
                atomic_add_f(&sum_nb[row], pnb[q * 4 + r]);
            }
        }
    }
}

// -------- Stage 2: finalize (128 blocks; wave = 8 rows) + scalar fold ------
__global__ __launch_bounds__(256) void finalize_kernel(
    const float* __restrict__ inputs, const int* __restrict__ roi_label,
    const float* __restrict__ lut,
    const float* __restrict__ sum_bg, const float* __restrict__ sum_nb,
    float* __restrict__ accums, unsigned int* __restrict__ ticket,
    float* __restrict__ out)
{
    __shared__ float s_det[4], s_oim[4], s_nv[4];
    const int wid  = threadIdx.x >> 6;
    const int lane = threadIdx.x & 63;

    float det_a = 0.f, oim_a = 0.f, nv_a = 0.f;

    #pragma unroll 1
    for (int it = 0; it < 8; ++it) {
        const int row = blockIdx.x * 32 + wid * 8 + it;
        const int r   = roi_label[row];

        float dot = 0.f;
        {
            const int rc = r < 0 ? 0 : r;
            const f32x4 xi = *(const f32x4*)(inputs + (size_t)row * FEAT + lane * 4);
            const f32x4 li = *(const f32x4*)(lut + (size_t)rc * FEAT + lane * 4);
            #pragma unroll
            for (int jj = 0; jj < 4; ++jj)
                dot += bf2f((u16)f2bf(xi[jj])) * bf2f((u16)f2bf(li[jj]));
        }
        #pragma unroll
        for (int off = 32; off > 0; off >>= 1) dot += __shfl_xor(dot, off);

        if (lane == 0) {
            const float sbg = sum_bg[row];
            const float snb = sum_nb[row];
            const float inv = 1.f / (sbg + snb);
            const float cls0 = sbg * inv;
            const float cls1 = snb * inv;
            out[2 * row]     = cls0;
            out[2 * row + 1] = cls1;

            const float cs = (r >= -1) ? cls1 : cls0;
            const float om = 1.f - cs;
            det_a += -(0.25f * om * om * logf(cs)) * (1.f / (float)BATCH);
            nv_a  += (r >= -1) ? 1.f : 0.f;

            if (r >= 0) {
                const float logp = 30.f * dot - logf(snb);
                const float p    = expf(logp);
                const float om2  = 1.f - p;
                oim_a += -(0.25f * om2 * om2 * logp) * cls1 * cls1;
            }
        }
    }

    if (lane == 0) { s_det[wid] = det_a; s_oim[wid] = oim_a; s_nv[wid] = nv_a; }
    __syncthreads();
    if (threadIdx.x == 0) {
        atomic_add_f(&accums[0], s_det[0] + s_det[1] + s_det[2] + s_det[3]);
        atomic_add_f(&accums[1], s_oim[0] + s_oim[1] + s_oim[2] + s_oim[3]);
        atomic_add_f(&accums[2], s_nv[0] + s_nv[1] + s_nv[2] + s_nv[3]);
        __threadfence();
        const unsigned t = __hip_atomic_fetch_add(ticket, 1u, __ATOMIC_ACQ_REL,
                                                  __HIP_MEMORY_SCOPE_AGENT);
        if (t == gridDim.x - 1) {
            const float det = atomic_ld_f(&accums[0]);
            const float oim = atomic_ld_f(&accums[1]);
            float nv        = atomic_ld_f(&accums[2]);
            if (nv < 1.f) nv = 1.f;
            out[2 * BATCH]     = det;
            out[2 * BATCH + 1] = oim / nv;
        }
    }
}

extern "C" void kernel_launch(void* const* d_in, const int* in_sizes, int n_in,
                              void* d_out, int out_size, void* d_ws, size_t ws_size,
                              hipStream_t stream)
{
    const float* inputs = (const float*)d_in[0];
    const int*   roi    = (const int*)d_in[1];
    const float* lut    = (const float*)d_in[2];
    const float* cq     = (const float*)d_in[3];
    const float* cqb    = (const float*)d_in[4];
    float* out = (float*)d_out;

    if (ws_size >= (size_t)WS_NEED) {
        u16* tabt = (u16*)d_ws;
        u16* at   = (u16*)((char*)d_ws + TABT_BYTES);
        float* S  = (float*)((char*)d_ws + SUMS_OFF);
        prepass_kernel<<<PRE_BLOCKS, 256, 0, stream>>>(inputs, lut, cq, cqb, tabt, at, S);
        score_bf16_kernel<<<976, 256, 0, stream>>>(tabt, at, S, S + BATCH);
        finalize_kernel<<<128, 256, 0, stream>>>(
            inputs, roi, lut, S, S + BATCH, S + 2 * BATCH,
            (unsigned int*)(S + 2 * BATCH + 3), out);
    } else {
        float* S = (float*)d_ws;
        hipMemsetAsync(S, 0, SUMS_FLOATS * sizeof(float), stream);
        dim3 g1(61, 16);
        score_f32_kernel<<<g1, 256, 0, stream>>>(inputs, lut, cq, cqb, S, S + BATCH);
        finalize_kernel<<<128, 256, 0, stream>>>(
            inputs, roi, lut, S, S + BATCH, S + 2 * BATCH,
            (unsigned int*)(S + 2 * BATCH + 3), out);
    }
}